// Round 3
// baseline (228.700 us; speedup 1.0000x reference)
//
#include <hip/hip_runtime.h>
#include <hip/hip_cooperative_groups.h>

namespace cg = cooperative_groups;

#define NB 2
#define NG 1024
#define HEIGHT 128
#define WIDTH 128
#define HW (HEIGHT * WIDTH)
#define E10 4.5399931e-05f                 // exp(-10)

// ws layout (floats)
#define REC_U 0                            // unsorted records: 2048*16
#define REC_S 32768                        // sorted records:   2048*16
#define Z_U   65536                        // unsorted z:       2048
#define BBOX  67584                        // sorted bboxes:    2048*4 (dense float4)
#define PFX   75776                        // background prefix: 2*1025*8
#define PFX_STRIDE 8200
#define TCNT  92192                        // 512 tile counts (int)
#define TLIST 92704                        // 512 tiles * 1024 u16
#define RGBOF 354848                       // rendered rgb: 6*HW
#define P_ENT 453152                       // 32 entropy partials
#define P_L1D 453184                       // 512 depth-l1 partials
#define P_SSS 453696                       // 256 ssim partials
#define P_SSL 453952                       // 256 rgb-l1 partials
// record: [0]px [1]py [2]hx [3]hy [4]i00 [5]i01 [6]i11 [7]op [8]c0 [9]c1 [10]c2 [11]z [12]e10op [13..15]pad
// prefix P_k (stride 8): [0]Tt [1]Ur [2]Ug [3]Ub [4]Ud  (background affine of ranks [0,k))

__global__ __launch_bounds__(1024, 4) void k_mega(
    const float* __restrict__ g, const float* __restrict__ intr,
    const float* __restrict__ trgb, const float* __restrict__ tgt_d,
    float* __restrict__ ws, float* __restrict__ out)
{
    __shared__ float smem[5120];           // 20 KB, reused per phase
    cg::grid_group grid = cg::this_grid();
    const int tid = threadIdx.x;
    const int bid = blockIdx.x;
    const int lane = tid & 63;
    const int wv = tid >> 6;

    // ======== A: per-gaussian preprocess (blocks 0,1; 1024 gaussians each) ==
    if (bid < 2) {
        int idx = bid * 1024 + tid;        // 0..2047, b == bid
        int b = bid;
        const float* row = g + (size_t)idx * 38;
        float mx = row[0], my = row[1], mz = row[2];
        float sx = row[3], sy = row[4], sz = row[5];
        float qw = row[6], qx = row[7], qy = row[8], qz = row[9];
        float op = row[10];
        float sh0 = row[11], sh1 = row[12], sh2 = row[13];
        float fx = intr[b * 9 + 0], fy = intr[b * 9 + 4];
        float cx = intr[b * 9 + 2], cy = intr[b * 9 + 5];

        float z = fmaxf(mz, 1e-4f);
        float px = fx * mx / z + cx;
        float py = fy * my / z + cy;

        float r00 = 1.f - 2.f * (qy * qy + qz * qz), r01 = 2.f * (qx * qy - qw * qz), r02 = 2.f * (qx * qz + qw * qy);
        float r10 = 2.f * (qx * qy + qw * qz), r11 = 1.f - 2.f * (qx * qx + qz * qz), r12 = 2.f * (qy * qz - qw * qx);
        float r20 = 2.f * (qx * qz - qw * qy), r21 = 2.f * (qy * qz + qw * qx), r22 = 1.f - 2.f * (qx * qx + qy * qy);
        float a00 = r00 * sx, a01 = r01 * sy, a02 = r02 * sz;
        float a10 = r10 * sx, a11 = r11 * sy, a12 = r12 * sz;
        float a20 = r20 * sx, a21 = r21 * sy, a22 = r22 * sz;
        float m00 = a00 * a00 + a01 * a01 + a02 * a02;
        float m01 = a00 * a10 + a01 * a11 + a02 * a12;
        float m02 = a00 * a20 + a01 * a21 + a02 * a22;
        float m11 = a10 * a10 + a11 * a11 + a12 * a12;
        float m12 = a10 * a20 + a11 * a21 + a12 * a22;
        float m22 = a20 * a20 + a21 * a21 + a22 * a22;

        float zc = fmaxf(mz, 1e-6f);
        float aJ = fx / zc, bJ = -fx * mx / (zc * zc);
        float cJ = fy / zc, dJ = -fy * my / (zc * zc);
        float c00 = aJ * aJ * m00 + 2.f * aJ * bJ * m02 + bJ * bJ * m22 + 0.3f;
        float c01 = cJ * (aJ * m01 + bJ * m12) + dJ * (aJ * m02 + bJ * m22);
        float c11 = cJ * cJ * m11 + 2.f * cJ * dJ * m12 + dJ * dJ * m22 + 0.3f;
        float det = fmaxf(c00 * c11 - c01 * c01, 1e-8f);
        float i00 = c11 / det;
        float i11 = c00 / det;
        float i01 = -c01 / det;

        const float C0c = 0.28209479177387814f;
        float col0 = fminf(fmaxf(sh0 * C0c + 0.5f, 0.f), 1.f);
        float col1 = fminf(fmaxf(sh1 * C0c + 0.5f, 0.f), 1.f);
        float col2 = fminf(fmaxf(sh2 * C0c + 0.5f, 0.f), 1.f);

        float hx = sqrtf(20.f * c00);      // power>-10 ellipse bbox half-extents
        float hy = sqrtf(20.f * c11);

        float* rec = ws + REC_U + (size_t)idx * 16;
        rec[0] = px; rec[1] = py; rec[2] = hx; rec[3] = hy;
        rec[4] = i00; rec[5] = i01; rec[6] = i11; rec[7] = op;
        rec[8] = col0; rec[9] = col1; rec[10] = col2; rec[11] = z;
        rec[12] = E10 * op; rec[13] = 0.f; rec[14] = 0.f; rec[15] = 0.f;
        ws[Z_U + idx] = z;

        float o = fminf(fmaxf(op, 1e-6f), 1.f - 1e-6f);
        float ent = -(o * logf(o) + (1.f - o) * logf(1.f - o));
        for (int off = 32; off > 0; off >>= 1) ent += __shfl_down(ent, off, 64);
        if (lane == 0) ws[P_ENT + (bid << 4) + wv] = ent;
    }
    grid.sync();

    // ======== B: rank sort + scatter (blocks 0..7) ==========================
    if (bid < 8) {
        int b = bid >> 2, part = bid & 3;
        float* zs = smem;                  // 1024 floats
        int* spi = (int*)(smem + 1024);    // 1024 ints
        if (tid < 256) ((float4*)zs)[tid] = ((const float4*)(ws + Z_U + (b << 10)))[tid];
        __syncthreads();
        int c = tid & 255, jq = tid >> 8;  // 4-way j split
        int il = part * 256 + c;
        float zi = zs[il];
        int rank = 0;
        int j0 = jq << 8;
#pragma unroll 4
        for (int j = j0; j < j0 + 256; j += 4) {
            float4 zq = *(const float4*)(zs + j);
            rank += (zq.x < zi) || (zq.x == zi && (j + 0) < il);
            rank += (zq.y < zi) || (zq.y == zi && (j + 1) < il);
            rank += (zq.z < zi) || (zq.z == zi && (j + 2) < il);
            rank += (zq.w < zi) || (zq.w == zi && (j + 3) < il);
        }
        spi[tid] = rank;
        __syncthreads();
        if (tid < 256) {
            int r = spi[tid] + spi[tid + 256] + spi[tid + 512] + spi[tid + 768];
            int gi = (b << 10) + part * 256 + tid;
            const float4* src = (const float4*)(ws + REC_U + (size_t)gi * 16);
            float4 r0 = src[0], r1 = src[1], r2 = src[2], r3 = src[3];
            float4* dst = (float4*)(ws + REC_S + (size_t)((b << 10) + r) * 16);
            dst[0] = r0; dst[1] = r1; dst[2] = r2; dst[3] = r3;
            ((float4*)(ws + BBOX))[(b << 10) + r] = r0;   // dense bbox for bin
        }
    }
    grid.sync();

    // ======== C: background prefix scan (blocks 0,1) + tile bin (all) =======
    if (bid < 2) {
        int b = bid;
        const float* rec = ws + REC_S + (size_t)((b << 10) + tid) * 16;
        float4 f1 = ((const float4*)rec)[1];  // i00 i01 i11 op
        float4 f2 = ((const float4*)rec)[2];  // c0 c1 c2 z
        float a10 = E10 * f1.w;
        float t = 1.f - a10;
        float ur = a10 * f2.x, ug = a10 * f2.y, ub = a10 * f2.z, ud = a10 * f2.w;
        // wave-level inclusive affine scan (compose: first=left, second=self)
#pragma unroll
        for (int off = 1; off < 64; off <<= 1) {
            float pt = __shfl_up(t, off, 64);
            float pr = __shfl_up(ur, off, 64);
            float pg = __shfl_up(ug, off, 64);
            float pb = __shfl_up(ub, off, 64);
            float pd = __shfl_up(ud, off, 64);
            if (lane >= off) {
                ur = pr + pt * ur; ug = pg + pt * ug;
                ub = pb + pt * ub; ud = pd + pt * ud;
                t = pt * t;
            }
        }
        if (lane == 63) {
            smem[wv * 5 + 0] = t;  smem[wv * 5 + 1] = ur; smem[wv * 5 + 2] = ug;
            smem[wv * 5 + 3] = ub; smem[wv * 5 + 4] = ud;
        }
        __syncthreads();
        float Pt = 1.f, Pur = 0.f, Pug = 0.f, Pub = 0.f, Pud = 0.f;
        for (int i = 0; i < wv; i++) {     // compose earlier wave aggregates
            float at = smem[i * 5], ar = smem[i * 5 + 1], ag = smem[i * 5 + 2];
            float ab = smem[i * 5 + 3], ad = smem[i * 5 + 4];
            Pur = Pur + Pt * ar; Pug = Pug + Pt * ag;
            Pub = Pub + Pt * ab; Pud = Pud + Pt * ad;
            Pt = Pt * at;
        }
        float gt = Pt * t;
        float gur = Pur + Pt * ur, gug = Pug + Pt * ug;
        float gub = Pub + Pt * ub, gud = Pud + Pt * ud;
        float* P = ws + PFX + (size_t)b * PFX_STRIDE;
        ((float4*)(P + (size_t)(tid + 1) * 8))[0] = make_float4(gt, gur, gug, gub);
        P[(size_t)(tid + 1) * 8 + 4] = gud;
        if (tid == 0) {
            ((float4*)P)[0] = make_float4(1.f, 0.f, 0.f, 0.f);
            P[4] = 0.f;
        }
    }
    // bin: every block handles tiles bid and bid+256 (thread = z-rank element)
    {
        int* wcnt = (int*)smem;
        for (int t2 = 0; t2 < 2; t2++) {
            __syncthreads();               // protects smem reuse
            int blk_t = bid + t2 * 256;
            int b = blk_t >> 8, tt = blk_t & 255;
            float x0f = (float)((tt & 15) * 8), x1f = x0f + 7.f;
            float y0f = (float)((tt >> 4) * 8), y1f = y0f + 7.f;
            float4 bb = ((const float4*)(ws + BBOX))[(b << 10) + tid];
            bool ov = (bb.x + bb.z >= x0f) && (bb.x - bb.z <= x1f) &&
                      (bb.y + bb.w >= y0f) && (bb.y - bb.w <= y1f);
            unsigned long long mask = __ballot(ov);
            int loff = __popcll(mask & ((1ull << lane) - 1ull));
            if (lane == 0) wcnt[wv] = (int)__popcll(mask);
            __syncthreads();
            int woff = 0, totc = 0;
#pragma unroll
            for (int i = 0; i < 16; i++) {
                int ci = wcnt[i];
                woff += (i < wv) ? ci : 0;
                totc += ci;
            }
            unsigned short* list = (unsigned short*)(ws + TLIST) + (size_t)blk_t * 1024;
            if (ov) list[woff + loff] = (unsigned short)tid;
            if (tid == 0) ((int*)(ws + TCNT))[blk_t] = totc;
        }
    }
    grid.sync();

    // ======== D: render (every block: tiles bid, bid+256) ===================
    for (int t2 = 0; t2 < 2; t2++) {
        __syncthreads();                   // protects comb reuse across tiles
        int blk_t = bid + t2 * 256;
        int b = blk_t >> 8, tt = blk_t & 255;
        int x0 = (tt & 15) * 8, y0 = (tt >> 4) * 8;
        int x = x0 + (lane & 7), y = y0 + (lane >> 3);
        float xf = (float)x, yf = (float)y;

        int cnt = ((const int*)(ws + TCNT))[blk_t];
        const unsigned short* list = (const unsigned short*)(ws + TLIST) + (size_t)blk_t * 1024;
        const float* P = ws + PFX + (size_t)b * PFX_STRIDE;
        const float* recs = ws + REC_S + (size_t)(b << 10) * 16;

        int m = (cnt + 15) >> 4;
        int p0 = wv * m; if (p0 > cnt) p0 = cnt;
        int p1 = p0 + m; if (p1 > cnt) p1 = cnt;
        int s0 = (p0 == 0) ? 0 : (int)list[p0 - 1] + 1;

        float4 Pa = *(const float4*)(P + (size_t)s0 * 8);
        float Pud = P[(size_t)s0 * 8 + 4];
        float inv0 = 1.f / Pa.x;           // 1/Tt_s0 (in [1, 1.05])
        float Pur = Pa.y, Pug = Pa.z, Pub = Pa.w;

        float tau = 1.f, cr = 0.f, cgn = 0.f, cb = 0.f, cd = 0.f;
        for (int p = p0; p < p1; p++) {
            int r = (int)list[p];
            float4 Qa = *(const float4*)(P + (size_t)r * 8);
            float Qud = P[(size_t)r * 8 + 4];
            const float* rec = recs + (size_t)r * 16;
            float4 g0 = ((const float4*)rec)[0];  // px py hx hy
            float4 g1 = ((const float4*)rec)[1];  // i00 i01 i11 op
            float4 g2 = ((const float4*)rec)[2];  // c0 c1 c2 z
            float kap = tau * inv0;
            // background run [prev, r)
            cr += kap * (Qa.y - Pur);
            cgn += kap * (Qa.z - Pug);
            cb += kap * (Qa.w - Pub);
            cd += kap * (Qud - Pud);
            // item r (exact: clamp covers out-of-ellipse pixels)
            float dx = xf - g0.x, dy = yf - g0.y;
            float q = g1.x * dx * dx + 2.f * g1.y * dx * dy + g1.z * dy * dy;
            float pw = fminf(fmaxf(-0.5f * q, -10.f), 0.f);
            float a = fminf(__expf(pw) * g1.w, 0.99f);
            float w = kap * Qa.x * a;
            cr += w * g2.x; cgn += w * g2.y; cb += w * g2.z; cd += w * g2.w;
            float a10 = E10 * g1.w;
            tau *= (1.f - a) * (1.f + a10 * (1.f + a10));  // /(1-a10) to 2nd order
            // advance prefix boundary to r+1 in-register
            float s = Qa.x * a10;
            Pur = Qa.y + s * g2.x;
            Pug = Qa.z + s * g2.y;
            Pub = Qa.w + s * g2.z;
            Pud = Qud + s * g2.w;
        }
        int e0 = (wv == 15) ? NG : ((p1 == 0) ? 0 : (int)list[p1 - 1] + 1);
        float4 Ea = *(const float4*)(P + (size_t)e0 * 8);
        float Eud = P[(size_t)e0 * 8 + 4];
        float kapf = tau * inv0;
        cr += kapf * (Ea.y - Pur);
        cgn += kapf * (Ea.z - Pug);
        cb += kapf * (Ea.w - Pub);
        cd += kapf * (Eud - Pud);
        float T = tau * Ea.x * inv0;

        smem[0 * 1024 + tid] = T;
        smem[1 * 1024 + tid] = cr;
        smem[2 * 1024 + tid] = cgn;
        smem[3 * 1024 + tid] = cb;
        smem[4 * 1024 + tid] = cd;
        __syncthreads();

        if (tid < 64) {
            float T0 = smem[tid], r0 = smem[1024 + tid], g0 = smem[2048 + tid];
            float b0 = smem[3072 + tid], d0 = smem[4096 + tid];
#pragma unroll
            for (int sgi = 1; sgi < 16; sgi++) {
                int j = sgi * 64 + tid;
                r0 += T0 * smem[1024 + j];
                g0 += T0 * smem[2048 + j];
                b0 += T0 * smem[3072 + j];
                d0 += T0 * smem[4096 + j];
                T0 *= smem[j];
            }
            r0 = fminf(fmaxf(r0, 0.f), 1.f);
            g0 = fminf(fmaxf(g0, 0.f), 1.f);
            b0 = fminf(fmaxf(b0, 0.f), 1.f);
            float* rgb = ws + RGBOF;
            rgb[((b * 3 + 0) * HEIGHT + y) * WIDTH + x] = r0;
            rgb[((b * 3 + 1) * HEIGHT + y) * WIDTH + x] = g0;
            rgb[((b * 3 + 2) * HEIGHT + y) * WIDTH + x] = b0;
            float l1d = fabsf(d0 - tgt_d[(b * HEIGHT + y) * WIDTH + x]);
            for (int off = 32; off > 0; off >>= 1) l1d += __shfl_down(l1d, off, 64);
            if (tid == 0) ws[P_L1D + blk_t] = l1d;
        }
    }
    grid.sync();

    // ======== E: SSIM + rgb L1 (384 outputs per block) ======================
    {
        float ssim = 0.f, l1 = 0.f;
        if (tid < 384) {
            int idx = bid * 384 + tid;     // < 98304
            const float* img1 = ws + RGBOF;
            int bc = idx >> 14;
            int pix = idx & (HW - 1);
            int y = pix >> 7, x = pix & 127;

            float gg[7];
            float gs = 0.f;
#pragma unroll
            for (int i = 0; i < 7; i++) {
                float c = (float)(i - 3);
                gg[i] = __expf(-c * c / 4.5f);
                gs += gg[i];
            }
#pragma unroll
            for (int i = 0; i < 7; i++) gg[i] /= gs;

            float mu1 = 0.f, mu2 = 0.f, s11 = 0.f, s22 = 0.f, s12 = 0.f;
            int plane = bc * HW;
#pragma unroll
            for (int dy = -3; dy <= 3; dy++) {
                int yy = y + dy;
#pragma unroll
                for (int dx = -3; dx <= 3; dx++) {
                    int xx = x + dx;
                    float w = gg[dy + 3] * gg[dx + 3];
                    float i1 = 0.f, i2 = 0.f;
                    if (yy >= 0 && yy < HEIGHT && xx >= 0 && xx < WIDTH) {
                        int o = plane + yy * WIDTH + xx;
                        i1 = img1[o];
                        i2 = trgb[o];
                    }
                    mu1 += w * i1;
                    mu2 += w * i2;
                    s11 += w * i1 * i1;
                    s22 += w * i2 * i2;
                    s12 += w * i1 * i2;
                }
            }
            float v1 = s11 - mu1 * mu1;
            float v2 = s22 - mu2 * mu2;
            float cv = s12 - mu1 * mu2;
            const float C1 = 1e-4f, C2 = 9e-4f;
            ssim = ((2.f * mu1 * mu2 + C1) * (2.f * cv + C2)) /
                   ((mu1 * mu1 + mu2 * mu2 + C1) * (v1 + v2 + C2));
            l1 = fabsf(img1[idx] - trgb[idx]);
        }
        for (int off = 32; off > 0; off >>= 1) {
            ssim += __shfl_down(ssim, off, 64);
            l1 += __shfl_down(l1, off, 64);
        }
        if (lane == 0) { smem[wv] = ssim; smem[16 + wv] = l1; }
        __syncthreads();
        if (tid == 0) {
            float ss = 0.f, sl = 0.f;
#pragma unroll
            for (int i = 0; i < 16; i++) { ss += smem[i]; sl += smem[16 + i]; }
            ws[P_SSS + bid] = ss;
            ws[P_SSL + bid] = sl;
        }
    }
    grid.sync();

    // ======== F: final reduce (block 0) =====================================
    if (bid == 0) {
        float d = 0.f, ss = 0.f, sl = 0.f, e = 0.f;
        if (tid < 512) d = ws[P_L1D + tid];
        if (tid < 256) { ss = ws[P_SSS + tid]; sl = ws[P_SSL + tid]; }
        if (tid < 32) e = ws[P_ENT + tid];
        for (int off = 32; off > 0; off >>= 1) {
            d += __shfl_down(d, off, 64);
            ss += __shfl_down(ss, off, 64);
            sl += __shfl_down(sl, off, 64);
            e += __shfl_down(e, off, 64);
        }
        if (lane == 0) {
            smem[wv] = d; smem[16 + wv] = ss; smem[32 + wv] = sl; smem[48 + wv] = e;
        }
        __syncthreads();
        if (tid == 0) {
            float rd = 0.f, rss = 0.f, rsl = 0.f, re = 0.f;
#pragma unroll
            for (int i = 0; i < 16; i++) {
                rd += smem[i]; rss += smem[16 + i]; rsl += smem[32 + i]; re += smem[48 + i];
            }
            float l1r = rsl / (float)(NB * 3 * HW);
            float ssim = rss / (float)(NB * 3 * HW);
            float l1d = rd / (float)(NB * HW);
            float opa = re / (float)(NB * NG);
            out[0] = 0.8f * l1r + 0.2f * (1.f - ssim) + 0.5f * l1d + 0.01f * opa;
        }
    }
}

extern "C" void kernel_launch(void* const* d_in, const int* in_sizes, int n_in,
                              void* d_out, int out_size, void* d_ws, size_t ws_size,
                              hipStream_t stream) {
    const float* g = (const float*)d_in[0];
    const float* intr = (const float*)d_in[1];
    const float* trgb = (const float*)d_in[2];
    const float* tdep = (const float*)d_in[3];
    float* ws = (float*)d_ws;
    float* out = (float*)d_out;

    void* args[] = {(void*)&g, (void*)&intr, (void*)&trgb, (void*)&tdep,
                    (void*)&ws, (void*)&out};
    hipLaunchCooperativeKernel((void*)k_mega, dim3(256), dim3(1024), args, 0, stream);
}

// Round 4
// 95.937 us; speedup vs baseline: 2.3839x; 2.3839x over previous
//
#include <hip/hip_runtime.h>

#define NB 2
#define NG 1024
#define HEIGHT 128
#define WIDTH 128
#define HW (HEIGHT * WIDTH)
#define E10 4.5399931e-05f                 // exp(-10)

// ws layout (float indices)
#define REC_S 0                            // sorted records: 2048*16
#define P_ENT 32768                        // 32 entropy partials
#define P_L1D 32800                        // 512 depth-l1 partials
#define P_SSS 33312                        // 384 ssim partials
#define P_SSL 33696                        // 384 rgb-l1 partials
#define CNT_I 34080                        // int: finished-ssim-block counter
#define RGBOF 34084                        // rendered rgb: 6*HW
// record: [0]px [1]py [2]hx [3]hy [4]i00 [5]i01 [6]i11 [7]op [8]c0 [9]c1 [10]c2 [11]z [12..15] unused

__device__ inline float blk_reduce(float v, float* sh) {
    for (int off = 32; off > 0; off >>= 1) v += __shfl_down(v, off, 64);
    int lane = threadIdx.x & 63;
    int w = threadIdx.x >> 6;
    __syncthreads();
    if (lane == 0) sh[w] = v;
    __syncthreads();
    float s = 0.f;
    if (threadIdx.x == 0) {
        int nw = (blockDim.x + 63) >> 6;
        for (int i = 0; i < nw; i++) s += sh[i];
    }
    return s;  // valid on thread 0 only
}

// ========== K1: fused pre + rank (32 blocks x 256) ==========================
// Block = (batch, group-of-64). z loaded directly from g (rank needs only z),
// u64 keys (bits(z)<<10 | idx) reproduce stable-argsort tie-break exactly.
// Threads 0..63 then do the full per-gaussian preprocess and scatter to REC_S.
__global__ __launch_bounds__(256) void k_prerank(const float* __restrict__ g,
                                                 const float* __restrict__ intr,
                                                 float* __restrict__ ws) {
    __shared__ __align__(16) unsigned long long zkey[NG];
    __shared__ int sp[256];
    int bid = blockIdx.x;        // 0..31
    int b = bid >> 4;            // batch
    int grp = bid & 15;          // which 64 gaussians
    int tid = threadIdx.x;

    // stage all 1024 sort keys of this batch
#pragma unroll
    for (int q = 0; q < 4; q++) {
        int j = tid + q * 256;
        float z = fmaxf(g[(size_t)((b << 10) + j) * 38 + 2], 1e-4f);
        zkey[j] = ((unsigned long long)__float_as_uint(z) << 10) | (unsigned)j;
    }
    __syncthreads();

    int il = (grp << 6) + (tid & 63);
    int jq = tid >> 6;           // j-quarter (wave-uniform)
    unsigned long long ki = zkey[il];
    int rank = 0;
    int j0 = jq << 8;
#pragma unroll 4
    for (int j = j0; j < j0 + 256; j += 2) {
        ulonglong2 kk = *(const ulonglong2*)(zkey + j);  // uniform addr -> broadcast
        rank += (kk.x < ki);
        rank += (kk.y < ki);
    }
    sp[tid] = rank;
    __syncthreads();

    if (tid < 64) {
        int r = sp[tid] + sp[tid + 64] + sp[tid + 128] + sp[tid + 192];
        int idx = (b << 10) + il;
        const float* row = g + (size_t)idx * 38;
        float mx = row[0], my = row[1], mz = row[2];
        float sx = row[3], sy = row[4], sz = row[5];
        float qw = row[6], qx = row[7], qy = row[8], qz = row[9];
        float op = row[10];
        float sh0 = row[11], sh1 = row[12], sh2 = row[13];
        float fx = intr[b * 9 + 0], fy = intr[b * 9 + 4];
        float cx = intr[b * 9 + 2], cy = intr[b * 9 + 5];

        float z = fmaxf(mz, 1e-4f);
        float px = fx * mx / z + cx;
        float py = fy * my / z + cy;

        float r00 = 1.f - 2.f * (qy * qy + qz * qz), r01 = 2.f * (qx * qy - qw * qz), r02 = 2.f * (qx * qz + qw * qy);
        float r10 = 2.f * (qx * qy + qw * qz), r11 = 1.f - 2.f * (qx * qx + qz * qz), r12 = 2.f * (qy * qz - qw * qx);
        float r20 = 2.f * (qx * qz - qw * qy), r21 = 2.f * (qy * qz + qw * qx), r22 = 1.f - 2.f * (qx * qx + qy * qy);
        float a00 = r00 * sx, a01 = r01 * sy, a02 = r02 * sz;
        float a10 = r10 * sx, a11 = r11 * sy, a12 = r12 * sz;
        float a20 = r20 * sx, a21 = r21 * sy, a22 = r22 * sz;
        float m00 = a00 * a00 + a01 * a01 + a02 * a02;
        float m01 = a00 * a10 + a01 * a11 + a02 * a12;
        float m02 = a00 * a20 + a01 * a21 + a02 * a22;
        float m11 = a10 * a10 + a11 * a11 + a12 * a12;
        float m12 = a10 * a20 + a11 * a21 + a12 * a22;
        float m22 = a20 * a20 + a21 * a21 + a22 * a22;

        float zc = fmaxf(mz, 1e-6f);
        float aJ = fx / zc, bJ = -fx * mx / (zc * zc);
        float cJ = fy / zc, dJ = -fy * my / (zc * zc);
        float c00 = aJ * aJ * m00 + 2.f * aJ * bJ * m02 + bJ * bJ * m22 + 0.3f;
        float c01 = cJ * (aJ * m01 + bJ * m12) + dJ * (aJ * m02 + bJ * m22);
        float c11 = cJ * cJ * m11 + 2.f * cJ * dJ * m12 + dJ * dJ * m22 + 0.3f;
        float det = fmaxf(c00 * c11 - c01 * c01, 1e-8f);
        float i00 = c11 / det;
        float i11 = c00 / det;
        float i01 = -c01 / det;

        const float C0c = 0.28209479177387814f;
        float col0 = fminf(fmaxf(sh0 * C0c + 0.5f, 0.f), 1.f);
        float col1 = fminf(fmaxf(sh1 * C0c + 0.5f, 0.f), 1.f);
        float col2 = fminf(fmaxf(sh2 * C0c + 0.5f, 0.f), 1.f);

        float hx = sqrtf(20.f * c00);      // power>-10 ellipse bbox half-extents
        float hy = sqrtf(20.f * c11);

        float* rec = ws + REC_S + (size_t)((b << 10) + r) * 16;
        ((float4*)rec)[0] = make_float4(px, py, hx, hy);
        ((float4*)rec)[1] = make_float4(i00, i01, i11, op);
        ((float4*)rec)[2] = make_float4(col0, col1, col2, z);

        float o = fminf(fmaxf(op, 1e-6f), 1.f - 1e-6f);
        float ent = -(o * logf(o) + (1.f - o) * logf(1.f - o));
        for (int off = 32; off > 0; off >>= 1) ent += __shfl_down(ent, off, 64);
        if (tid == 0) ws[P_ENT + bid] = ent;
    }
    if (bid == 0 && tid == 0) ((int*)ws)[CNT_I] = 0;  // for K3 last-block pattern
}

// ========== K2: fused scan + bin + render (512 blocks x 1024) ===============
// Per tile-block: redundant block-local background-prefix scan into LDS,
// ballot-compacted tile list in LDS, then the verified prefix-quotient render.
__global__ __launch_bounds__(1024, 8) void k_render(const float* __restrict__ tgt_d,
                                                    float* __restrict__ ws) {
    __shared__ float4 sPa[NG + 1];         // prefix: Tt, Ur, Ug, Ub
    __shared__ float sPud[NG + 1];         // prefix: Ud
    __shared__ unsigned short slist[NG];
    __shared__ int swcnt[16];
    __shared__ float sagg[16 * 5];
    __shared__ float comb[5][1024];

    int tid = threadIdx.x;
    int lane = tid & 63;
    int wv = tid >> 6;
    int blk = blockIdx.x;  // 512 tiles
    int b = blk >> 8;
    int tt = blk & 255;
    int x0 = (tt & 15) * 8, y0 = (tt >> 4) * 8;
    int x = x0 + (lane & 7), y = y0 + (lane >> 3);
    float xf = (float)x, yf = (float)y;
    float x0f = (float)x0, x1f = x0f + 7.f;
    float y0f = (float)y0, y1f = y0f + 7.f;

    const float* recs = ws + REC_S + (size_t)(b << 10) * 16;

    // ---- load my sorted record (rank == tid) ----
    const float* rec = recs + (size_t)tid * 16;
    float4 q0 = ((const float4*)rec)[0];   // px py hx hy
    float4 q1 = ((const float4*)rec)[1];   // i00 i01 i11 op
    float4 q2 = ((const float4*)rec)[2];   // c0 c1 c2 z

    // ---- bin: ballot-compact overlap list (z-order preserved) ----
    bool ov = (q0.x + q0.z >= x0f) && (q0.x - q0.z <= x1f) &&
              (q0.y + q0.w >= y0f) && (q0.y - q0.w <= y1f);
    unsigned long long mask = __ballot(ov);
    int loff = __popcll(mask & ((1ull << lane) - 1ull));
    if (lane == 0) swcnt[wv] = (int)__popcll(mask);

    // ---- scan: wave-level inclusive affine scan of background maps ----
    float a10 = E10 * q1.w;
    float t = 1.f - a10;
    float ur = a10 * q2.x, ug = a10 * q2.y, ub = a10 * q2.z, ud = a10 * q2.w;
#pragma unroll
    for (int off = 1; off < 64; off <<= 1) {
        float pt = __shfl_up(t, off, 64);
        float pr = __shfl_up(ur, off, 64);
        float pg = __shfl_up(ug, off, 64);
        float pb = __shfl_up(ub, off, 64);
        float pd = __shfl_up(ud, off, 64);
        if (lane >= off) {
            ur = pr + pt * ur; ug = pg + pt * ug;
            ub = pb + pt * ub; ud = pd + pt * ud;
            t = pt * t;
        }
    }
    if (lane == 63) {
        sagg[wv * 5 + 0] = t;  sagg[wv * 5 + 1] = ur; sagg[wv * 5 + 2] = ug;
        sagg[wv * 5 + 3] = ub; sagg[wv * 5 + 4] = ud;
    }
    __syncthreads();

    // bin offsets + total
    int woff = 0, cnt = 0;
#pragma unroll
    for (int i = 0; i < 16; i++) {
        int ci = swcnt[i];
        woff += (i < wv) ? ci : 0;
        cnt += ci;
    }
    if (ov) slist[woff + loff] = (unsigned short)tid;

    // block-combine scan: compose earlier wave aggregates
    float Pt = 1.f, Pur = 0.f, Pug = 0.f, Pub = 0.f, Pud0 = 0.f;
    for (int i = 0; i < wv; i++) {
        float at = sagg[i * 5], ar = sagg[i * 5 + 1], ag = sagg[i * 5 + 2];
        float ab = sagg[i * 5 + 3], ad = sagg[i * 5 + 4];
        Pur = Pur + Pt * ar; Pug = Pug + Pt * ag;
        Pub = Pub + Pt * ab; Pud0 = Pud0 + Pt * ad;
        Pt = Pt * at;
    }
    sPa[tid + 1] = make_float4(Pt * t, Pur + Pt * ur, Pug + Pt * ug, Pub + Pt * ub);
    sPud[tid + 1] = Pud0 + Pt * ud;
    if (tid == 0) {
        sPa[0] = make_float4(1.f, 0.f, 0.f, 0.f);
        sPud[0] = 0.f;
    }
    __syncthreads();

    // ---- render: 16 waves split the tile list into contiguous z-chunks ----
    int m = (cnt + 15) >> 4;
    int p0 = wv * m; if (p0 > cnt) p0 = cnt;
    int p1 = p0 + m; if (p1 > cnt) p1 = cnt;
    int s0 = (p0 == 0) ? 0 : (int)slist[p0 - 1] + 1;

    float4 Pa = sPa[s0];
    float Pud = sPud[s0];
    float inv0 = 1.f / Pa.x;               // 1/Tt_s0 (in [1, 1.05])
    float Pur2 = Pa.y, Pug2 = Pa.z, Pub2 = Pa.w;

    float tau = 1.f, cr = 0.f, cgn = 0.f, cb = 0.f, cd = 0.f;
    for (int p = p0; p < p1; p++) {
        int r = (int)slist[p];
        float4 Qa = sPa[r];
        float Qud = sPud[r];
        const float* rp = recs + (size_t)r * 16;
        float4 g0 = ((const float4*)rp)[0];  // px py hx hy
        float4 g1 = ((const float4*)rp)[1];  // i00 i01 i11 op
        float4 g2 = ((const float4*)rp)[2];  // c0 c1 c2 z
        float kap = tau * inv0;
        // background run [prev, r)
        cr += kap * (Qa.y - Pur2);
        cgn += kap * (Qa.z - Pug2);
        cb += kap * (Qa.w - Pub2);
        cd += kap * (Qud - Pud);
        // item r (exact: clamp covers out-of-ellipse pixels)
        float dx = xf - g0.x, dy = yf - g0.y;
        float q = g1.x * dx * dx + 2.f * g1.y * dx * dy + g1.z * dy * dy;
        float pw = fminf(fmaxf(-0.5f * q, -10.f), 0.f);
        float a = fminf(__expf(pw) * g1.w, 0.99f);
        float w = kap * Qa.x * a;
        cr += w * g2.x; cgn += w * g2.y; cb += w * g2.z; cd += w * g2.w;
        float a10i = E10 * g1.w;
        tau *= (1.f - a) * (1.f + a10i * (1.f + a10i));  // /(1-a10) to 2nd order
        // advance prefix boundary to r+1 in-register
        float s = Qa.x * a10i;
        Pur2 = Qa.y + s * g2.x;
        Pug2 = Qa.z + s * g2.y;
        Pub2 = Qa.w + s * g2.z;
        Pud = Qud + s * g2.w;
    }
    int e0 = (wv == 15) ? NG : ((p1 == 0) ? 0 : (int)slist[p1 - 1] + 1);
    float4 Ea = sPa[e0];
    float Eud = sPud[e0];
    float kapf = tau * inv0;
    cr += kapf * (Ea.y - Pur2);
    cgn += kapf * (Ea.z - Pug2);
    cb += kapf * (Ea.w - Pub2);
    cd += kapf * (Eud - Pud);
    float T = tau * Ea.x * inv0;

    comb[0][tid] = T;
    comb[1][tid] = cr;
    comb[2][tid] = cgn;
    comb[3][tid] = cb;
    comb[4][tid] = cd;
    __syncthreads();

    if (tid < 64) {
        float T0 = comb[0][tid], r0 = comb[1][tid], g0 = comb[2][tid];
        float b0 = comb[3][tid], d0 = comb[4][tid];
#pragma unroll
        for (int sgi = 1; sgi < 16; sgi++) {
            int j = sgi * 64 + tid;
            r0 += T0 * comb[1][j];
            g0 += T0 * comb[2][j];
            b0 += T0 * comb[3][j];
            d0 += T0 * comb[4][j];
            T0 *= comb[0][j];
        }
        r0 = fminf(fmaxf(r0, 0.f), 1.f);
        g0 = fminf(fmaxf(g0, 0.f), 1.f);
        b0 = fminf(fmaxf(b0, 0.f), 1.f);
        float* rgb = ws + RGBOF;
        rgb[((b * 3 + 0) * HEIGHT + y) * WIDTH + x] = r0;
        rgb[((b * 3 + 1) * HEIGHT + y) * WIDTH + x] = g0;
        rgb[((b * 3 + 2) * HEIGHT + y) * WIDTH + x] = b0;
        float l1d = fabsf(d0 - tgt_d[(b * HEIGHT + y) * WIDTH + x]);
        for (int off = 32; off > 0; off >>= 1) l1d += __shfl_down(l1d, off, 64);
        if (tid == 0) ws[P_L1D + blk] = l1d;
    }
}

// ========== K3: SSIM + rgb L1 + fused final reduce (384 blocks x 256) =======
__global__ __launch_bounds__(256) void k_ssim_final(const float* __restrict__ tgt_rgb,
                                                    float* __restrict__ ws,
                                                    float* __restrict__ out) {
    __shared__ float sh[8];
    __shared__ int sflag;
    int bid = blockIdx.x;
    int idx = bid * 256 + threadIdx.x;     // < 98304
    const float* img1 = ws + RGBOF;
    int bc = idx >> 14;
    int pix = idx & (HW - 1);
    int y = pix >> 7, x = pix & 127;

    float gg[7];
    float gs = 0.f;
#pragma unroll
    for (int i = 0; i < 7; i++) {
        float c = (float)(i - 3);
        gg[i] = __expf(-c * c / 4.5f);
        gs += gg[i];
    }
#pragma unroll
    for (int i = 0; i < 7; i++) gg[i] /= gs;

    float mu1 = 0.f, mu2 = 0.f, s11 = 0.f, s22 = 0.f, s12 = 0.f;
    int plane = bc * HW;
#pragma unroll
    for (int dy = -3; dy <= 3; dy++) {
        int yy = y + dy;
#pragma unroll
        for (int dx = -3; dx <= 3; dx++) {
            int xx = x + dx;
            float w = gg[dy + 3] * gg[dx + 3];
            float i1 = 0.f, i2 = 0.f;
            if (yy >= 0 && yy < HEIGHT && xx >= 0 && xx < WIDTH) {
                int o = plane + yy * WIDTH + xx;
                i1 = img1[o];
                i2 = tgt_rgb[o];
            }
            mu1 += w * i1;
            mu2 += w * i2;
            s11 += w * i1 * i1;
            s22 += w * i2 * i2;
            s12 += w * i1 * i2;
        }
    }
    float v1 = s11 - mu1 * mu1;
    float v2 = s22 - mu2 * mu2;
    float cv = s12 - mu1 * mu2;
    const float C1 = 1e-4f, C2 = 9e-4f;
    float ssim = ((2.f * mu1 * mu2 + C1) * (2.f * cv + C2)) /
                 ((mu1 * mu1 + mu2 * mu2 + C1) * (v1 + v2 + C2));
    float l1 = fabsf(img1[idx] - tgt_rgb[idx]);

    float s_ssim = blk_reduce(ssim, sh);
    float s_l1 = blk_reduce(l1, sh);

    // last-block-done: partials -> fence -> counter; final block reduces all
    if (threadIdx.x == 0) {
        ws[P_SSS + bid] = s_ssim;
        ws[P_SSL + bid] = s_l1;
        __threadfence();
        int old = atomicAdd((int*)ws + CNT_I, 1);
        sflag = (old == 383) ? 1 : 0;
    }
    __syncthreads();
    if (sflag) {
        __threadfence();                   // acquire: see all blocks' partials
        float d = 0.f, ss = 0.f, sl = 0.f, e = 0.f;
        for (int i = threadIdx.x; i < 512; i += 256) d += ws[P_L1D + i];
        for (int i = threadIdx.x; i < 384; i += 256) { ss += ws[P_SSS + i]; sl += ws[P_SSL + i]; }
        if (threadIdx.x < 32) e = ws[P_ENT + threadIdx.x];
        float rd_ = blk_reduce(d, sh);
        float rss = blk_reduce(ss, sh);
        float rsl = blk_reduce(sl, sh);
        float re = blk_reduce(e, sh);
        if (threadIdx.x == 0) {
            float l1r = rsl / (float)(NB * 3 * HW);
            float ssimv = rss / (float)(NB * 3 * HW);
            float l1d = rd_ / (float)(NB * HW);
            float opa = re / (float)(NB * NG);
            out[0] = 0.8f * l1r + 0.2f * (1.f - ssimv) + 0.5f * l1d + 0.01f * opa;
        }
    }
}

extern "C" void kernel_launch(void* const* d_in, const int* in_sizes, int n_in,
                              void* d_out, int out_size, void* d_ws, size_t ws_size,
                              hipStream_t stream) {
    const float* g = (const float*)d_in[0];
    const float* intr = (const float*)d_in[1];
    const float* trgb = (const float*)d_in[2];
    const float* tdep = (const float*)d_in[3];
    float* ws = (float*)d_ws;
    float* out = (float*)d_out;

    hipLaunchKernelGGL(k_prerank, dim3(32), dim3(256), 0, stream, g, intr, ws);
    hipLaunchKernelGGL(k_render, dim3(NB * 256), dim3(1024), 0, stream, tdep, ws);
    hipLaunchKernelGGL(k_ssim_final, dim3((NB * 3 * HW) / 256), dim3(256), 0, stream, trgb, ws, out);
}

// Round 5
// 92.819 us; speedup vs baseline: 2.4639x; 1.0336x over previous
//
#include <hip/hip_runtime.h>

#define NB 2
#define NG 1024
#define HEIGHT 128
#define WIDTH 128
#define HW (HEIGHT * WIDTH)
#define E10 4.5399931e-05f                 // exp(-10)
#define PW 134                             // padded width (3px apron)
#define PPLANE (PW * PW)                   // padded plane = 17956

// ws layout (float indices)
#define REC_S 0                            // sorted records: 2048*16
#define P_ENT 32768                        // 32 entropy partials
#define P_L1D 32800                        // 512 depth-l1 partials
#define P_SSS 33312                        // 192 ssim partials
#define P_SSL 33504                        // 192 rgb-l1 partials
#define CNT_I 33696                        // int: finished-ssim-block counter
#define RGBOF 33700                        // padded rgb: 6*134*134 = 107736
// record: [0]px [1]py [2]hx [3]hy [4]i00 [5]i01 [6]i11 [7]op [8]c0 [9]c1 [10]c2 [11]z [12..15] unused

__device__ inline float blk_reduce(float v, float* sh) {
    for (int off = 32; off > 0; off >>= 1) v += __shfl_down(v, off, 64);
    int lane = threadIdx.x & 63;
    int w = threadIdx.x >> 6;
    __syncthreads();
    if (lane == 0) sh[w] = v;
    __syncthreads();
    float s = 0.f;
    if (threadIdx.x == 0) {
        int nw = (blockDim.x + 63) >> 6;
        for (int i = 0; i < nw; i++) s += sh[i];
    }
    return s;  // valid on thread 0 only
}

// ========== K1: fused pre + rank (32 blocks x 256) ==========================
// Block = (batch, group-of-64). z loaded directly from g (rank needs only z),
// u64 keys (bits(z)<<10 | idx) reproduce stable-argsort tie-break exactly.
// Threads 0..63 then do the full per-gaussian preprocess and scatter to REC_S.
// Spare work: zero the padded rgb region (apron must be 0 for k_ssim).
__global__ __launch_bounds__(256) void k_prerank(const float* __restrict__ g,
                                                 const float* __restrict__ intr,
                                                 float* __restrict__ ws) {
    __shared__ __align__(16) unsigned long long zkey[NG];
    __shared__ int sp[256];
    int bid = blockIdx.x;        // 0..31
    int b = bid >> 4;            // batch
    int grp = bid & 15;          // which 64 gaussians
    int tid = threadIdx.x;

    // stage all 1024 sort keys of this batch
#pragma unroll
    for (int q = 0; q < 4; q++) {
        int j = tid + q * 256;
        float z = fmaxf(g[(size_t)((b << 10) + j) * 38 + 2], 1e-4f);
        zkey[j] = ((unsigned long long)__float_as_uint(z) << 10) | (unsigned)j;
    }
    __syncthreads();

    int il = (grp << 6) + (tid & 63);
    int jq = tid >> 6;           // j-quarter (wave-uniform)
    unsigned long long ki = zkey[il];
    int rank = 0;
    int j0 = jq << 8;
#pragma unroll 4
    for (int j = j0; j < j0 + 256; j += 2) {
        ulonglong2 kk = *(const ulonglong2*)(zkey + j);  // uniform addr -> broadcast
        rank += (kk.x < ki);
        rank += (kk.y < ki);
    }
    sp[tid] = rank;
    __syncthreads();

    if (tid < 64) {
        int r = sp[tid] + sp[tid + 64] + sp[tid + 128] + sp[tid + 192];
        int idx = (b << 10) + il;
        const float* row = g + (size_t)idx * 38;
        float mx = row[0], my = row[1], mz = row[2];
        float sx = row[3], sy = row[4], sz = row[5];
        float qw = row[6], qx = row[7], qy = row[8], qz = row[9];
        float op = row[10];
        float sh0 = row[11], sh1 = row[12], sh2 = row[13];
        float fx = intr[b * 9 + 0], fy = intr[b * 9 + 4];
        float cx = intr[b * 9 + 2], cy = intr[b * 9 + 5];

        float z = fmaxf(mz, 1e-4f);
        float px = fx * mx / z + cx;
        float py = fy * my / z + cy;

        float r00 = 1.f - 2.f * (qy * qy + qz * qz), r01 = 2.f * (qx * qy - qw * qz), r02 = 2.f * (qx * qz + qw * qy);
        float r10 = 2.f * (qx * qy + qw * qz), r11 = 1.f - 2.f * (qx * qx + qz * qz), r12 = 2.f * (qy * qz - qw * qx);
        float r20 = 2.f * (qx * qz - qw * qy), r21 = 2.f * (qy * qz + qw * qx), r22 = 1.f - 2.f * (qx * qx + qy * qy);
        float a00 = r00 * sx, a01 = r01 * sy, a02 = r02 * sz;
        float a10 = r10 * sx, a11 = r11 * sy, a12 = r12 * sz;
        float a20 = r20 * sx, a21 = r21 * sy, a22 = r22 * sz;
        float m00 = a00 * a00 + a01 * a01 + a02 * a02;
        float m01 = a00 * a10 + a01 * a11 + a02 * a12;
        float m02 = a00 * a20 + a01 * a21 + a02 * a22;
        float m11 = a10 * a10 + a11 * a11 + a12 * a12;
        float m12 = a10 * a20 + a11 * a21 + a12 * a22;
        float m22 = a20 * a20 + a21 * a21 + a22 * a22;

        float zc = fmaxf(mz, 1e-6f);
        float aJ = fx / zc, bJ = -fx * mx / (zc * zc);
        float cJ = fy / zc, dJ = -fy * my / (zc * zc);
        float c00 = aJ * aJ * m00 + 2.f * aJ * bJ * m02 + bJ * bJ * m22 + 0.3f;
        float c01 = cJ * (aJ * m01 + bJ * m12) + dJ * (aJ * m02 + bJ * m22);
        float c11 = cJ * cJ * m11 + 2.f * cJ * dJ * m12 + dJ * dJ * m22 + 0.3f;
        float det = fmaxf(c00 * c11 - c01 * c01, 1e-8f);
        float i00 = c11 / det;
        float i11 = c00 / det;
        float i01 = -c01 / det;

        const float C0c = 0.28209479177387814f;
        float col0 = fminf(fmaxf(sh0 * C0c + 0.5f, 0.f), 1.f);
        float col1 = fminf(fmaxf(sh1 * C0c + 0.5f, 0.f), 1.f);
        float col2 = fminf(fmaxf(sh2 * C0c + 0.5f, 0.f), 1.f);

        float hx = sqrtf(20.f * c00);      // power>-10 ellipse bbox half-extents
        float hy = sqrtf(20.f * c11);

        float* rec = ws + REC_S + (size_t)((b << 10) + r) * 16;
        ((float4*)rec)[0] = make_float4(px, py, hx, hy);
        ((float4*)rec)[1] = make_float4(i00, i01, i11, op);
        ((float4*)rec)[2] = make_float4(col0, col1, col2, z);

        float o = fminf(fmaxf(op, 1e-6f), 1.f - 1e-6f);
        float ent = -(o * logf(o) + (1.f - o) * logf(1.f - o));
        for (int off = 32; off > 0; off >>= 1) ent += __shfl_down(ent, off, 64);
        if (tid == 0) ws[P_ENT + bid] = ent;
    }
    // zero padded rgb region (interior overwritten later by k_render)
    for (int i = bid * 256 + tid; i < 6 * PPLANE; i += 32 * 256)
        ws[RGBOF + i] = 0.f;
    if (bid == 0 && tid == 0) ((int*)ws)[CNT_I] = 0;  // for K3 last-block pattern
}

// ========== K2: fused scan + bin + render (512 blocks x 1024) ===============
// Per tile-block: redundant block-local background-prefix scan into LDS,
// ballot-compacted tile list in LDS, then the verified prefix-quotient render.
__global__ __launch_bounds__(1024, 8) void k_render(const float* __restrict__ tgt_d,
                                                    float* __restrict__ ws) {
    __shared__ float4 sPa[NG + 1];         // prefix: Tt, Ur, Ug, Ub
    __shared__ float sPud[NG + 1];         // prefix: Ud
    __shared__ unsigned short slist[NG];
    __shared__ int swcnt[16];
    __shared__ float sagg[16 * 5];
    __shared__ float comb[5][1024];

    int tid = threadIdx.x;
    int lane = tid & 63;
    int wv = tid >> 6;
    int blk = blockIdx.x;  // 512 tiles
    int b = blk >> 8;
    int tt = blk & 255;
    int x0 = (tt & 15) * 8, y0 = (tt >> 4) * 8;
    int x = x0 + (lane & 7), y = y0 + (lane >> 3);
    float xf = (float)x, yf = (float)y;
    float x0f = (float)x0, x1f = x0f + 7.f;
    float y0f = (float)y0, y1f = y0f + 7.f;

    const float* recs = ws + REC_S + (size_t)(b << 10) * 16;

    // ---- load my sorted record (rank == tid) ----
    const float* rec = recs + (size_t)tid * 16;
    float4 q0 = ((const float4*)rec)[0];   // px py hx hy
    float4 q1 = ((const float4*)rec)[1];   // i00 i01 i11 op
    float4 q2 = ((const float4*)rec)[2];   // c0 c1 c2 z

    // ---- bin: ballot-compact overlap list (z-order preserved) ----
    bool ov = (q0.x + q0.z >= x0f) && (q0.x - q0.z <= x1f) &&
              (q0.y + q0.w >= y0f) && (q0.y - q0.w <= y1f);
    unsigned long long mask = __ballot(ov);
    int loff = __popcll(mask & ((1ull << lane) - 1ull));
    if (lane == 0) swcnt[wv] = (int)__popcll(mask);

    // ---- scan: wave-level inclusive affine scan of background maps ----
    float a10 = E10 * q1.w;
    float t = 1.f - a10;
    float ur = a10 * q2.x, ug = a10 * q2.y, ub = a10 * q2.z, ud = a10 * q2.w;
#pragma unroll
    for (int off = 1; off < 64; off <<= 1) {
        float pt = __shfl_up(t, off, 64);
        float pr = __shfl_up(ur, off, 64);
        float pg = __shfl_up(ug, off, 64);
        float pb = __shfl_up(ub, off, 64);
        float pd = __shfl_up(ud, off, 64);
        if (lane >= off) {
            ur = pr + pt * ur; ug = pg + pt * ug;
            ub = pb + pt * ub; ud = pd + pt * ud;
            t = pt * t;
        }
    }
    if (lane == 63) {
        sagg[wv * 5 + 0] = t;  sagg[wv * 5 + 1] = ur; sagg[wv * 5 + 2] = ug;
        sagg[wv * 5 + 3] = ub; sagg[wv * 5 + 4] = ud;
    }
    __syncthreads();

    // bin offsets + total
    int woff = 0, cnt = 0;
#pragma unroll
    for (int i = 0; i < 16; i++) {
        int ci = swcnt[i];
        woff += (i < wv) ? ci : 0;
        cnt += ci;
    }
    if (ov) slist[woff + loff] = (unsigned short)tid;

    // wave 0 lanes 0..15: exclusive affine scan over the 16 wave aggregates
    if (tid < 16) {
        float at = sagg[tid * 5 + 0], ar = sagg[tid * 5 + 1], ag = sagg[tid * 5 + 2];
        float ab = sagg[tid * 5 + 3], ad = sagg[tid * 5 + 4];
#pragma unroll
        for (int off = 1; off < 16; off <<= 1) {
            float pt = __shfl_up(at, off, 16);
            float pr = __shfl_up(ar, off, 16);
            float pg = __shfl_up(ag, off, 16);
            float pb = __shfl_up(ab, off, 16);
            float pd = __shfl_up(ad, off, 16);
            if (tid >= off) {
                ar = pr + pt * ar; ag = pg + pt * ag;
                ab = pb + pt * ab; ad = pd + pt * ad;
                at = pt * at;
            }
        }
        float eat = __shfl_up(at, 1, 16);
        float ear = __shfl_up(ar, 1, 16);
        float eag = __shfl_up(ag, 1, 16);
        float eab = __shfl_up(ab, 1, 16);
        float ead = __shfl_up(ad, 1, 16);
        if (tid == 0) { eat = 1.f; ear = 0.f; eag = 0.f; eab = 0.f; ead = 0.f; }
        sagg[tid * 5 + 0] = eat; sagg[tid * 5 + 1] = ear; sagg[tid * 5 + 2] = eag;
        sagg[tid * 5 + 3] = eab; sagg[tid * 5 + 4] = ead;
    }
    __syncthreads();

    // compose: (exclusive aggregate of my wave) then (my in-wave inclusive)
    {
        float Pt = sagg[wv * 5 + 0], Pur = sagg[wv * 5 + 1], Pug = sagg[wv * 5 + 2];
        float Pub = sagg[wv * 5 + 3], Pud0 = sagg[wv * 5 + 4];
        sPa[tid + 1] = make_float4(Pt * t, Pur + Pt * ur, Pug + Pt * ug, Pub + Pt * ub);
        sPud[tid + 1] = Pud0 + Pt * ud;
    }
    if (tid == 0) {
        sPa[0] = make_float4(1.f, 0.f, 0.f, 0.f);
        sPud[0] = 0.f;
    }
    __syncthreads();

    // ---- render: 16 waves split the tile list into contiguous z-chunks ----
    int m = (cnt + 15) >> 4;
    int p0 = wv * m; if (p0 > cnt) p0 = cnt;
    int p1 = p0 + m; if (p1 > cnt) p1 = cnt;
    int s0 = (p0 == 0) ? 0 : (int)slist[p0 - 1] + 1;

    float4 Pa = sPa[s0];
    float Pud = sPud[s0];
    float inv0 = 1.f / Pa.x;               // 1/Tt_s0 (in [1, 1.05])
    float Pur2 = Pa.y, Pug2 = Pa.z, Pub2 = Pa.w;

    float tau = 1.f, cr = 0.f, cgn = 0.f, cb = 0.f, cd = 0.f;
    int r = (p0 < p1) ? (int)slist[p0] : 0;
    for (int p = p0; p < p1; p++) {
        int rn = (p + 1 < p1) ? (int)slist[p + 1] : 0;   // 1-deep prefetch
        float4 Qa = sPa[r];
        float Qud = sPud[r];
        const float* rp = recs + (size_t)r * 16;
        float4 g0 = ((const float4*)rp)[0];  // px py hx hy
        float4 g1 = ((const float4*)rp)[1];  // i00 i01 i11 op
        float4 g2 = ((const float4*)rp)[2];  // c0 c1 c2 z
        float kap = tau * inv0;
        // background run [prev, r)
        cr += kap * (Qa.y - Pur2);
        cgn += kap * (Qa.z - Pug2);
        cb += kap * (Qa.w - Pub2);
        cd += kap * (Qud - Pud);
        // item r (exact: clamp covers out-of-ellipse pixels)
        float dx = xf - g0.x, dy = yf - g0.y;
        float q = g1.x * dx * dx + 2.f * g1.y * dx * dy + g1.z * dy * dy;
        float pw = fminf(fmaxf(-0.5f * q, -10.f), 0.f);
        float a = fminf(__expf(pw) * g1.w, 0.99f);
        float w = kap * Qa.x * a;
        cr += w * g2.x; cgn += w * g2.y; cb += w * g2.z; cd += w * g2.w;
        float a10i = E10 * g1.w;
        tau *= (1.f - a) * (1.f + a10i * (1.f + a10i));  // /(1-a10) to 2nd order
        // advance prefix boundary to r+1 in-register
        float s = Qa.x * a10i;
        Pur2 = Qa.y + s * g2.x;
        Pug2 = Qa.z + s * g2.y;
        Pub2 = Qa.w + s * g2.z;
        Pud = Qud + s * g2.w;
        r = rn;
    }
    int e0 = (wv == 15) ? NG : ((p1 == 0) ? 0 : (int)slist[p1 - 1] + 1);
    float4 Ea = sPa[e0];
    float Eud = sPud[e0];
    float kapf = tau * inv0;
    cr += kapf * (Ea.y - Pur2);
    cgn += kapf * (Ea.z - Pug2);
    cb += kapf * (Ea.w - Pub2);
    cd += kapf * (Eud - Pud);
    float T = tau * Ea.x * inv0;

    comb[0][tid] = T;
    comb[1][tid] = cr;
    comb[2][tid] = cgn;
    comb[3][tid] = cb;
    comb[4][tid] = cd;
    __syncthreads();

    if (tid < 64) {
        float T0 = comb[0][tid], r0 = comb[1][tid], g0 = comb[2][tid];
        float b0 = comb[3][tid], d0 = comb[4][tid];
#pragma unroll
        for (int sgi = 1; sgi < 16; sgi++) {
            int j = sgi * 64 + tid;
            r0 += T0 * comb[1][j];
            g0 += T0 * comb[2][j];
            b0 += T0 * comb[3][j];
            d0 += T0 * comb[4][j];
            T0 *= comb[0][j];
        }
        r0 = fminf(fmaxf(r0, 0.f), 1.f);
        g0 = fminf(fmaxf(g0, 0.f), 1.f);
        b0 = fminf(fmaxf(b0, 0.f), 1.f);
        float* rgb = ws + RGBOF;
        int pofs = (y + 3) * PW + (x + 3);
        rgb[(b * 3 + 0) * PPLANE + pofs] = r0;
        rgb[(b * 3 + 1) * PPLANE + pofs] = g0;
        rgb[(b * 3 + 2) * PPLANE + pofs] = b0;
        float l1d = fabsf(d0 - tgt_d[(b * HEIGHT + y) * WIDTH + x]);
        for (int off = 32; off > 0; off >>= 1) l1d += __shfl_down(l1d, off, 64);
        if (tid == 0) ws[P_L1D + blk] = l1d;
    }
}

// ========== K3: SSIM + rgb L1 + fused final reduce (192 blocks x 256) =======
// Block = (plane, 8-row strip, 64-col half). Stage img1 (padded, no checks)
// and target (checked) strips into LDS; 49-tap window entirely from LDS.
__global__ __launch_bounds__(256) void k_ssim_final(const float* __restrict__ tgt_rgb,
                                                    float* __restrict__ ws,
                                                    float* __restrict__ out) {
    __shared__ float s1[14 * 70];
    __shared__ float s2[14 * 70];
    __shared__ float sh[8];
    __shared__ int sflag;
    int bid = blockIdx.x;                  // 0..191
    int tid = threadIdx.x;
    int p = bid >> 5;                      // plane 0..5 (= b*3+ch)
    int sy = (bid >> 1) & 15;              // row strip
    int hx2 = bid & 1;                     // col half
    int y0 = sy * 8, x0 = hx2 * 64;

    // stage: img1 from padded ws (no bounds checks), tgt with zero-fill
    const float* img1p = ws + RGBOF + (size_t)p * PPLANE;
    const float* tgtp = tgt_rgb + (size_t)p * HW;
    for (int i = tid; i < 14 * 70; i += 256) {
        int r = i / 70, c = i - r * 70;
        s1[i] = img1p[(y0 + r) * PW + (x0 + c)];
        int yy = y0 + r - 3, xx = x0 + c - 3;
        float v = 0.f;
        if (yy >= 0 && yy < HEIGHT && xx >= 0 && xx < WIDTH)
            v = tgtp[yy * WIDTH + xx];
        s2[i] = v;
    }
    __syncthreads();

    float gg[7];
    float gs = 0.f;
#pragma unroll
    for (int i = 0; i < 7; i++) {
        float c = (float)(i - 3);
        gg[i] = __expf(-c * c / 4.5f);
        gs += gg[i];
    }
#pragma unroll
    for (int i = 0; i < 7; i++) gg[i] /= gs;

    int row = tid >> 5;                    // 0..7
    int colb = (tid & 31) * 2;             // 0..62
    float ssim_acc = 0.f, l1_acc = 0.f;
#pragma unroll
    for (int j = 0; j < 2; j++) {
        int c = colb + j;
        float mu1 = 0.f, mu2 = 0.f, s11 = 0.f, s22 = 0.f, s12 = 0.f;
#pragma unroll
        for (int dy = 0; dy < 7; dy++) {
            int rb = (row + dy) * 70 + c;
#pragma unroll
            for (int dx = 0; dx < 7; dx++) {
                float w = gg[dy] * gg[dx];
                float i1 = s1[rb + dx];
                float i2 = s2[rb + dx];
                mu1 += w * i1;
                mu2 += w * i2;
                s11 += w * i1 * i1;
                s22 += w * i2 * i2;
                s12 += w * i1 * i2;
            }
        }
        float v1 = s11 - mu1 * mu1;
        float v2 = s22 - mu2 * mu2;
        float cv = s12 - mu1 * mu2;
        const float C1 = 1e-4f, C2 = 9e-4f;
        ssim_acc += ((2.f * mu1 * mu2 + C1) * (2.f * cv + C2)) /
                    ((mu1 * mu1 + mu2 * mu2 + C1) * (v1 + v2 + C2));
        int ctr = (row + 3) * 70 + c + 3;
        l1_acc += fabsf(s1[ctr] - s2[ctr]);
    }

    float s_ssim = blk_reduce(ssim_acc, sh);
    float s_l1 = blk_reduce(l1_acc, sh);

    // last-block-done: partials -> fence -> counter; final block reduces all
    if (tid == 0) {
        ws[P_SSS + bid] = s_ssim;
        ws[P_SSL + bid] = s_l1;
        __threadfence();
        int old = atomicAdd((int*)ws + CNT_I, 1);
        sflag = (old == 191) ? 1 : 0;
    }
    __syncthreads();
    if (sflag) {
        __threadfence();                   // acquire: see all blocks' partials
        float d = 0.f, ss = 0.f, sl = 0.f, e = 0.f;
        for (int i = tid; i < 512; i += 256) d += ws[P_L1D + i];
        if (tid < 192) { ss = ws[P_SSS + tid]; sl = ws[P_SSL + tid]; }
        if (tid < 32) e = ws[P_ENT + tid];
        float rd_ = blk_reduce(d, sh);
        float rss = blk_reduce(ss, sh);
        float rsl = blk_reduce(sl, sh);
        float re = blk_reduce(e, sh);
        if (tid == 0) {
            float l1r = rsl / (float)(NB * 3 * HW);
            float ssimv = rss / (float)(NB * 3 * HW);
            float l1d = rd_ / (float)(NB * HW);
            float opa = re / (float)(NB * NG);
            out[0] = 0.8f * l1r + 0.2f * (1.f - ssimv) + 0.5f * l1d + 0.01f * opa;
        }
    }
}

extern "C" void kernel_launch(void* const* d_in, const int* in_sizes, int n_in,
                              void* d_out, int out_size, void* d_ws, size_t ws_size,
                              hipStream_t stream) {
    const float* g = (const float*)d_in[0];
    const float* intr = (const float*)d_in[1];
    const float* trgb = (const float*)d_in[2];
    const float* tdep = (const float*)d_in[3];
    float* ws = (float*)d_ws;
    float* out = (float*)d_out;

    hipLaunchKernelGGL(k_prerank, dim3(32), dim3(256), 0, stream, g, intr, ws);
    hipLaunchKernelGGL(k_render, dim3(NB * 256), dim3(1024), 0, stream, tdep, ws);
    hipLaunchKernelGGL(k_ssim_final, dim3(192), dim3(256), 0, stream, trgb, ws, out);
}